// Round 3
// baseline (80.580 us; speedup 1.0000x reference)
//
#include <hip/hip_runtime.h>

// SpatialDeformableTransformer, fused:
//   V = bicubic_resize(flow [8,64,64,2] -> [8,512,512,2])   (jax.image.resize "cubic")
//   x_s = V[...,0] + linspace(-1,1,512)[ox];  y_s = V[...,1] + linspace(-1,1,512)[oy]
//   out = bilinear_sample(U, x_s, y_s) with reference's exact conventions.
//
// Layout: block = 256 threads = one 16x16 output tile (256 pixels).
//   Phase 1: each thread computes ONE pixel's bicubic coord -> LDS (full VALU util).
//   Phase 2: 4 unrolled gather passes, 4 threads/pixel (one float4 channel-group
//   each) -> wave-coalesced corner loads, 16 independent loads of ILP per thread.

#define N_B    8
#define IN_HW  512
#define N_C    16
#define F_HW   64
#define OUTHW  512
#define TILE   16

// Keys cubic kernel, a = -0.5, exactly as jax.image._fill_keys_cubic_kernel
__device__ __forceinline__ float keys_w(float x) {
    if (x >= 2.0f) return 0.0f;
    if (x >= 1.0f) return ((-0.5f * x + 2.5f) * x - 4.0f) * x + 2.0f;
    return ((1.5f * x - 2.5f) * x) * x + 1.0f;
}

// jax compute_weight_mat semantics for 64 -> 512, scale = 8, translation = 0:
//   sample_f = (i + 0.5)/8 - 0.5; taps j = floor(sf)-1 .. +2; out-of-range taps
//   dropped; weights renormalized by the sum of included taps.
__device__ __forceinline__ int cubic_taps(int i, float w[4]) {
    float sf = (i + 0.5f) * 0.125f - 0.5f;
    int jf = (int)floorf(sf);
    float sum = 0.0f;
#pragma unroll
    for (int t = 0; t < 4; ++t) {
        int j = jf - 1 + t;
        float wt = 0.0f;
        if (j >= 0 && j < F_HW) wt = keys_w(fabsf(sf - (float)j));
        w[t] = wt;
        sum += wt;
    }
    float inv = 1.0f / sum;
#pragma unroll
    for (int t = 0; t < 4; ++t) w[t] *= inv;
    return jf - 1;
}

__global__ __launch_bounds__(256) void sdt_kernel(const float* __restrict__ U,
                                                  const float* __restrict__ flow,
                                                  float* __restrict__ out) {
    __shared__ float2 coords[TILE * TILE];   // sampling coords in input-pixel units

    const int tid = threadIdx.x;
    const int bid = blockIdx.x;
    const int tx = bid & 31;          // 32 tiles per row
    const int ty = (bid >> 5) & 31;   // 32 tile rows
    const int b  = bid >> 10;

    // ---- phase 1: every thread computes one pixel's sampling coordinate ----
    {
        const int px = tid & (TILE - 1);
        const int py = tid >> 4;
        const int ox = tx * TILE + px;
        const int oy = ty * TILE + py;

        float wx[4], wy[4];
        const int jx0 = cubic_taps(ox, wx);
        const int jy0 = cubic_taps(oy, wy);

        float vx = 0.0f, vy = 0.0f;
        const float* fb = flow + (size_t)b * (F_HW * F_HW * 2);
#pragma unroll
        for (int t = 0; t < 4; ++t) {
            const int jy = min(max(jy0 + t, 0), F_HW - 1);
            const float wyt = wy[t];
            const float* frow = fb + jy * (F_HW * 2);
#pragma unroll
            for (int s = 0; s < 4; ++s) {
                const int jx = min(max(jx0 + s, 0), F_HW - 1);
                const float w = wyt * wx[s];
                const float2 f2 = *(const float2*)(frow + jx * 2);
                vx = fmaf(w, f2.x, vx);
                vy = fmaf(w, f2.y, vy);
            }
        }
        const float xg = -1.0f + (2.0f / 511.0f) * (float)ox;
        const float yg = -1.0f + (2.0f / 511.0f) * (float)oy;
        // reference: x = (xs + 1) * W/2  (NOT (W-1)/2)
        coords[tid] = make_float2((vx + xg + 1.0f) * (IN_HW / 2.0f),
                                  (vy + yg + 1.0f) * (IN_HW / 2.0f));
    }
    __syncthreads();

    // ---- phase 2: 4 passes, 4 threads per pixel, fully unrolled for ILP ----
    const int chg  = tid & 3;          // channel group (float4)
    const int slot = tid >> 2;         // 0..63
#pragma unroll
    for (int it = 0; it < 4; ++it) {
        const int q  = it * 64 + slot;         // pixel within tile
        const float2 c = coords[q];
        const float x = c.x, y = c.y;

        const float fx0 = floorf(x);
        const float fy0 = floorf(y);
        const int x0 = min(max((int)fx0, 0), IN_HW - 1);
        const int x1 = min(max((int)fx0 + 1, 0), IN_HW - 1);
        const int y0 = min(max((int)fy0, 0), IN_HW - 1);
        const int y1 = min(max((int)fy0 + 1, 0), IN_HW - 1);
        // weights from CLIPPED corner coords (replicates reference exactly)
        const float x0f = (float)x0, x1f = (float)x1, y0f = (float)y0, y1f = (float)y1;
        const float wa = (x1f - x) * (y1f - y);
        const float wb = (x1f - x) * (y - y0f);
        const float wc = (x - x0f) * (y1f - y);
        const float wd = (x - x0f) * (y - y0f);

        const float4 a  = *((const float4*)(U + (((size_t)b * IN_HW + y0) * IN_HW + x0) * N_C) + chg);
        const float4 bb = *((const float4*)(U + (((size_t)b * IN_HW + y1) * IN_HW + x0) * N_C) + chg);
        const float4 cc = *((const float4*)(U + (((size_t)b * IN_HW + y0) * IN_HW + x1) * N_C) + chg);
        const float4 dd = *((const float4*)(U + (((size_t)b * IN_HW + y1) * IN_HW + x1) * N_C) + chg);
        float4 r;
        r.x = wa * a.x + wb * bb.x + wc * cc.x + wd * dd.x;
        r.y = wa * a.y + wb * bb.y + wc * cc.y + wd * dd.y;
        r.z = wa * a.z + wb * bb.z + wc * cc.z + wd * dd.z;
        r.w = wa * a.w + wb * bb.w + wc * cc.w + wd * dd.w;

        const int ox = tx * TILE + (q & (TILE - 1));
        const int oy = ty * TILE + (q >> 4);
        *((float4*)(out + (((size_t)b * OUTHW + oy) * OUTHW + ox) * N_C) + chg) = r;
    }
}

extern "C" void kernel_launch(void* const* d_in, const int* in_sizes, int n_in,
                              void* d_out, int out_size, void* d_ws, size_t ws_size,
                              hipStream_t stream) {
    const float* U    = (const float*)d_in[0];
    const float* flow = (const float*)d_in[1];
    float* out        = (float*)d_out;
    const int n_blocks = N_B * (OUTHW / TILE) * (OUTHW / TILE);  // 8192
    sdt_kernel<<<dim3(n_blocks), dim3(256), 0, stream>>>(U, flow, out);
}

// Round 5
// 51.543 us; speedup vs baseline: 1.5634x; 1.5634x over previous
//
#include <hip/hip_runtime.h>

// SpatialDeformableTransformer, fused:
//   V = bicubic_resize(flow [8,64,64,2] -> [8,512,512,2])   (jax.image.resize "cubic")
//   x_s = V[...,0] + linspace(-1,1,512)[ox];  y_s = V[...,1] + linspace(-1,1,512)[oy]
//   out = bilinear_sample(U, x_s, y_s) with reference's exact conventions.
//
// Block = 256 threads = one 16x16 output tile.
//   Phase 1: each thread computes one pixel's bicubic coord -> LDS.
//   Phase 2: 4 unrolled passes, 4 threads/pixel (one float4 channel-group each).
// R5 levers:
//   - nontemporal stores for out (via ext_vector_type float4 — the HIP
//     float4 class is rejected by __builtin_nontemporal_store): out is
//     write-once; keeping it out of L2/L3 leaves the 128 MiB U resident in
//     the 256 MiB Infinity Cache (U+out = exactly L3 capacity otherwise).
//   - XCD-chunked swizzle: wg -> (image = bid&7, tile = bid>>3) so each of
//     the 8 XCDs owns one full batch image; neighbor-tile gather reuse stays
//     in that XCD's private L2.

#define N_B    8
#define IN_HW  512
#define N_C    16
#define F_HW   64
#define OUTHW  512
#define TILE   16

typedef float fvec4 __attribute__((ext_vector_type(4)));

// Keys cubic kernel, a = -0.5, exactly as jax.image._fill_keys_cubic_kernel
__device__ __forceinline__ float keys_w(float x) {
    if (x >= 2.0f) return 0.0f;
    if (x >= 1.0f) return ((-0.5f * x + 2.5f) * x - 4.0f) * x + 2.0f;
    return ((1.5f * x - 2.5f) * x) * x + 1.0f;
}

// jax compute_weight_mat semantics for 64 -> 512, scale = 8, translation = 0:
//   sample_f = (i + 0.5)/8 - 0.5; taps j = floor(sf)-1 .. +2; out-of-range taps
//   dropped; weights renormalized by the sum of included taps.
__device__ __forceinline__ int cubic_taps(int i, float w[4]) {
    float sf = (i + 0.5f) * 0.125f - 0.5f;
    int jf = (int)floorf(sf);
    float sum = 0.0f;
#pragma unroll
    for (int t = 0; t < 4; ++t) {
        int j = jf - 1 + t;
        float wt = 0.0f;
        if (j >= 0 && j < F_HW) wt = keys_w(fabsf(sf - (float)j));
        w[t] = wt;
        sum += wt;
    }
    float inv = 1.0f / sum;
#pragma unroll
    for (int t = 0; t < 4; ++t) w[t] *= inv;
    return jf - 1;
}

__global__ __launch_bounds__(256) void sdt_kernel(const float* __restrict__ U,
                                                  const float* __restrict__ flow,
                                                  float* __restrict__ out) {
    __shared__ float2 coords[TILE * TILE];   // sampling coords in input-pixel units

    const int tid = threadIdx.x;
    // XCD-chunked swizzle: round-robin wg->XCD means bid&7 == XCD id.
    // Give XCD k batch-image k; tile index is bid>>3 (8192 wgs, 8192%8==0).
    const int b  = blockIdx.x & 7;
    const int t  = blockIdx.x >> 3;          // 0..1023 tile within image
    const int tx = t & 31;
    const int ty = t >> 5;

    // ---- phase 1: every thread computes one pixel's sampling coordinate ----
    {
        const int px = tid & (TILE - 1);
        const int py = tid >> 4;
        const int ox = tx * TILE + px;
        const int oy = ty * TILE + py;

        float wx[4], wy[4];
        const int jx0 = cubic_taps(ox, wx);
        const int jy0 = cubic_taps(oy, wy);

        float vx = 0.0f, vy = 0.0f;
        const float* fb = flow + (size_t)b * (F_HW * F_HW * 2);
#pragma unroll
        for (int s = 0; s < 4; ++s) {
            const int jy = min(max(jy0 + s, 0), F_HW - 1);
            const float wyt = wy[s];
            const float* frow = fb + jy * (F_HW * 2);
#pragma unroll
            for (int r = 0; r < 4; ++r) {
                const int jx = min(max(jx0 + r, 0), F_HW - 1);
                const float w = wyt * wx[r];
                const float2 f2 = *(const float2*)(frow + jx * 2);
                vx = fmaf(w, f2.x, vx);
                vy = fmaf(w, f2.y, vy);
            }
        }
        const float xg = -1.0f + (2.0f / 511.0f) * (float)ox;
        const float yg = -1.0f + (2.0f / 511.0f) * (float)oy;
        // reference: x = (xs + 1) * W/2  (NOT (W-1)/2)
        coords[tid] = make_float2((vx + xg + 1.0f) * (IN_HW / 2.0f),
                                  (vy + yg + 1.0f) * (IN_HW / 2.0f));
    }
    __syncthreads();

    // ---- phase 2: 4 passes, 4 threads per pixel, fully unrolled for ILP ----
    const int chg  = tid & 3;          // channel group (float4)
    const int slot = tid >> 2;         // 0..63
#pragma unroll
    for (int it = 0; it < 4; ++it) {
        const int q  = it * 64 + slot;         // pixel within tile
        const float2 c = coords[q];
        const float x = c.x, y = c.y;

        const float fx0 = floorf(x);
        const float fy0 = floorf(y);
        const int x0 = min(max((int)fx0, 0), IN_HW - 1);
        const int x1 = min(max((int)fx0 + 1, 0), IN_HW - 1);
        const int y0 = min(max((int)fy0, 0), IN_HW - 1);
        const int y1 = min(max((int)fy0 + 1, 0), IN_HW - 1);
        // weights from CLIPPED corner coords (replicates reference exactly)
        const float x0f = (float)x0, x1f = (float)x1, y0f = (float)y0, y1f = (float)y1;
        const float wa = (x1f - x) * (y1f - y);
        const float wb = (x1f - x) * (y - y0f);
        const float wc = (x - x0f) * (y1f - y);
        const float wd = (x - x0f) * (y - y0f);

        const fvec4 a  = *((const fvec4*)(U + (((size_t)b * IN_HW + y0) * IN_HW + x0) * N_C) + chg);
        const fvec4 bb = *((const fvec4*)(U + (((size_t)b * IN_HW + y1) * IN_HW + x0) * N_C) + chg);
        const fvec4 cc = *((const fvec4*)(U + (((size_t)b * IN_HW + y0) * IN_HW + x1) * N_C) + chg);
        const fvec4 dd = *((const fvec4*)(U + (((size_t)b * IN_HW + y1) * IN_HW + x1) * N_C) + chg);
        fvec4 r = wa * a + wb * bb + wc * cc + wd * dd;

        const int ox = tx * TILE + (q & (TILE - 1));
        const int oy = ty * TILE + (q >> 4);
        fvec4* O = (fvec4*)(out + (((size_t)b * OUTHW + oy) * OUTHW + ox) * N_C) + chg;
        __builtin_nontemporal_store(r, O);   // write-once stream: keep U in L3
    }
}

extern "C" void kernel_launch(void* const* d_in, const int* in_sizes, int n_in,
                              void* d_out, int out_size, void* d_ws, size_t ws_size,
                              hipStream_t stream) {
    const float* U    = (const float*)d_in[0];
    const float* flow = (const float*)d_in[1];
    float* out        = (float*)d_out;
    const int n_blocks = N_B * (OUTHW / TILE) * (OUTHW / TILE);  // 8192
    sdt_kernel<<<dim3(n_blocks), dim3(256), 0, stream>>>(U, flow, out);
}

// Round 6
// 51.484 us; speedup vs baseline: 1.5651x; 1.0011x over previous
//
#include <hip/hip_runtime.h>

// SpatialDeformableTransformer, fused:
//   V = bicubic_resize(flow [8,64,64,2] -> [8,512,512,2])   (jax.image.resize "cubic")
//   x_s = V[...,0] + linspace(-1,1,512)[ox];  y_s = V[...,1] + linspace(-1,1,512)[oy]
//   out = bilinear_sample(U, x_s, y_s) with reference's exact conventions.
//
// Block = 256 threads = one 16x16 output tile.
//   Phase 1: each thread computes one pixel's bicubic coord -> LDS.
//   Phase 2: addresses/weights for 4 pixels -> ALL 16 corner loads issued
//            back-to-back (MLP!) -> combine -> 4 nontemporal stores.
// Established levers kept from R5 (51.5 us):
//   - nontemporal stores (out is write-once; keeps U L3-resident: FETCH 190->65 MB)
//   - XCD-chunked swizzle (image = bid&7 -> one image per XCD's L2)
// R6 lever: VGPR 32 was throttling memory-level parallelism (only ~2 loads in
// flight). __launch_bounds__(256,4) + load-hoisting -> ~16 loads in flight.

#define N_B    8
#define IN_HW  512
#define N_C    16
#define F_HW   64
#define OUTHW  512
#define TILE   16

typedef float fvec4 __attribute__((ext_vector_type(4)));

// Keys cubic kernel, a = -0.5, exactly as jax.image._fill_keys_cubic_kernel
__device__ __forceinline__ float keys_w(float x) {
    if (x >= 2.0f) return 0.0f;
    if (x >= 1.0f) return ((-0.5f * x + 2.5f) * x - 4.0f) * x + 2.0f;
    return ((1.5f * x - 2.5f) * x) * x + 1.0f;
}

// jax compute_weight_mat semantics for 64 -> 512, scale = 8, translation = 0:
//   sample_f = (i + 0.5)/8 - 0.5; taps j = floor(sf)-1 .. +2; out-of-range taps
//   dropped; weights renormalized by the sum of included taps.
__device__ __forceinline__ int cubic_taps(int i, float w[4]) {
    float sf = (i + 0.5f) * 0.125f - 0.5f;
    int jf = (int)floorf(sf);
    float sum = 0.0f;
#pragma unroll
    for (int t = 0; t < 4; ++t) {
        int j = jf - 1 + t;
        float wt = 0.0f;
        if (j >= 0 && j < F_HW) wt = keys_w(fabsf(sf - (float)j));
        w[t] = wt;
        sum += wt;
    }
    float inv = 1.0f / sum;
#pragma unroll
    for (int t = 0; t < 4; ++t) w[t] *= inv;
    return jf - 1;
}

__global__ __launch_bounds__(256, 4) void sdt_kernel(const float* __restrict__ U,
                                                     const float* __restrict__ flow,
                                                     float* __restrict__ out) {
    __shared__ float2 coords[TILE * TILE];   // sampling coords in input-pixel units

    const int tid = threadIdx.x;
    // XCD-chunked swizzle: round-robin wg->XCD means bid&7 == XCD id.
    const int b  = blockIdx.x & 7;
    const int t  = blockIdx.x >> 3;          // 0..1023 tile within image
    const int tx = t & 31;
    const int ty = t >> 5;

    // ---- phase 1: every thread computes one pixel's sampling coordinate ----
    {
        const int px = tid & (TILE - 1);
        const int py = tid >> 4;
        const int ox = tx * TILE + px;
        const int oy = ty * TILE + py;

        float wxc[4], wyc[4];
        const int jx0 = cubic_taps(ox, wxc);
        const int jy0 = cubic_taps(oy, wyc);

        float vx = 0.0f, vy = 0.0f;
        const float* fb = flow + (size_t)b * (F_HW * F_HW * 2);
#pragma unroll
        for (int s = 0; s < 4; ++s) {
            const int jy = min(max(jy0 + s, 0), F_HW - 1);
            const float wyt = wyc[s];
            const float* frow = fb + jy * (F_HW * 2);
#pragma unroll
            for (int r = 0; r < 4; ++r) {
                const int jx = min(max(jx0 + r, 0), F_HW - 1);
                const float w = wyt * wxc[r];
                const float2 f2 = *(const float2*)(frow + jx * 2);
                vx = fmaf(w, f2.x, vx);
                vy = fmaf(w, f2.y, vy);
            }
        }
        const float xg = -1.0f + (2.0f / 511.0f) * (float)ox;
        const float yg = -1.0f + (2.0f / 511.0f) * (float)oy;
        // reference: x = (xs + 1) * W/2  (NOT (W-1)/2)
        coords[tid] = make_float2((vx + xg + 1.0f) * (IN_HW / 2.0f),
                                  (vy + yg + 1.0f) * (IN_HW / 2.0f));
    }
    __syncthreads();

    // ---- phase 2: 4 pixels/thread; hoist all 16 corner loads for MLP ----
    const int chg  = tid & 3;          // channel group (float4)
    const int slot = tid >> 2;         // 0..63

    const float* Ub = U + (size_t)b * (IN_HW * IN_HW * N_C);
    const fvec4* Pa[4]; const fvec4* Pb[4]; const fvec4* Pc[4]; const fvec4* Pd[4];
    float wa[4], wb[4], wc[4], wd[4];

#pragma unroll
    for (int it = 0; it < 4; ++it) {
        const int q  = it * 64 + slot;         // pixel within tile
        const float2 c = coords[q];
        const float x = c.x, y = c.y;

        const float fx0 = floorf(x);
        const float fy0 = floorf(y);
        const int x0 = min(max((int)fx0, 0), IN_HW - 1);
        const int x1 = min(max((int)fx0 + 1, 0), IN_HW - 1);
        const int y0 = min(max((int)fy0, 0), IN_HW - 1);
        const int y1 = min(max((int)fy0 + 1, 0), IN_HW - 1);
        // weights from CLIPPED corner coords (replicates reference exactly)
        const float x0f = (float)x0, x1f = (float)x1, y0f = (float)y0, y1f = (float)y1;
        wa[it] = (x1f - x) * (y1f - y);
        wb[it] = (x1f - x) * (y - y0f);
        wc[it] = (x - x0f) * (y1f - y);
        wd[it] = (x - x0f) * (y - y0f);

        Pa[it] = (const fvec4*)(Ub + ((size_t)y0 * IN_HW + x0) * N_C) + chg;
        Pb[it] = (const fvec4*)(Ub + ((size_t)y1 * IN_HW + x0) * N_C) + chg;
        Pc[it] = (const fvec4*)(Ub + ((size_t)y0 * IN_HW + x1) * N_C) + chg;
        Pd[it] = (const fvec4*)(Ub + ((size_t)y1 * IN_HW + x1) * N_C) + chg;
    }

    fvec4 A[4], B[4], C[4], D[4];
#pragma unroll
    for (int it = 0; it < 4; ++it) {
        A[it] = *Pa[it];
        B[it] = *Pb[it];
        C[it] = *Pc[it];
        D[it] = *Pd[it];
    }

#pragma unroll
    for (int it = 0; it < 4; ++it) {
        const fvec4 r = wa[it] * A[it] + wb[it] * B[it] + wc[it] * C[it] + wd[it] * D[it];
        const int q  = it * 64 + slot;
        const int ox = tx * TILE + (q & (TILE - 1));
        const int oy = ty * TILE + (q >> 4);
        fvec4* O = (fvec4*)(out + (((size_t)b * OUTHW + oy) * OUTHW + ox) * N_C) + chg;
        __builtin_nontemporal_store(r, O);   // write-once stream: keep U in L3
    }
}

extern "C" void kernel_launch(void* const* d_in, const int* in_sizes, int n_in,
                              void* d_out, int out_size, void* d_ws, size_t ws_size,
                              hipStream_t stream) {
    const float* U    = (const float*)d_in[0];
    const float* flow = (const float*)d_in[1];
    float* out        = (float*)d_out;
    const int n_blocks = N_B * (OUTHW / TILE) * (OUTHW / TILE);  // 8192
    sdt_kernel<<<dim3(n_blocks), dim3(256), 0, stream>>>(U, flow, out);
}

// Round 7
// 46.825 us; speedup vs baseline: 1.7209x; 1.0995x over previous
//
#include <hip/hip_runtime.h>

// SpatialDeformableTransformer, fused:
//   V = bicubic_resize(flow [8,64,64,2] -> [8,512,512,2])   (jax.image.resize "cubic")
//   x_s = V[...,0] + linspace(-1,1,512)[ox];  y_s = V[...,1] + linspace(-1,1,512)[oy]
//   out = bilinear_sample(U, x_s, y_s) with reference's exact conventions.
//
// Block = 256 threads = one 16x16 output tile.
// Established levers:
//   - nontemporal stores (write-once out; keeps U L3-resident: FETCH 190->65 MB)
//   - XCD-chunked swizzle (image = bid&7 -> one image per XCD's L2)
// R7 lever: SEPARABLE bicubic. jax cubic resize = per-dim weight matrices.
// Tap bases have closed form per tile: jxB = 2*tx-2, jyB = 2*ty-2 (6x6 patch).
//   step A (32 thr):  per-column x-taps, per-row y-taps (Keys a=-0.5, edge-renorm)
//   step B (96 thr):  H[6][16] horizontal pass (4 x-taps)
//   step C (256 thr): vertical pass (4 y-taps) -> sampling coord in LDS
// This removes the per-pixel 16-tap 2D accumulation (8192 FMA + 4096 float2
// loads per block) that made VALUBusy ~50% of clean wall clock.

#define N_B    8
#define IN_HW  512
#define N_C    16
#define F_HW   64
#define OUTHW  512
#define TILE   16

typedef float fvec4 __attribute__((ext_vector_type(4)));

// Keys cubic kernel, a = -0.5, exactly as jax.image._fill_keys_cubic_kernel
__device__ __forceinline__ float keys_w(float x) {
    if (x >= 2.0f) return 0.0f;
    if (x >= 1.0f) return ((-0.5f * x + 2.5f) * x - 4.0f) * x + 2.0f;
    return ((1.5f * x - 2.5f) * x) * x + 1.0f;
}

// jax compute_weight_mat semantics for 64 -> 512, scale = 8, translation = 0:
//   sample_f = (i + 0.5)/8 - 0.5; taps j = floor(sf)-1 .. +2; out-of-range taps
//   dropped; weights renormalized by the sum of included taps.
__device__ __forceinline__ int cubic_taps(int i, float w[4]) {
    float sf = (i + 0.5f) * 0.125f - 0.5f;
    int jf = (int)floorf(sf);
    float sum = 0.0f;
#pragma unroll
    for (int t = 0; t < 4; ++t) {
        int j = jf - 1 + t;
        float wt = 0.0f;
        if (j >= 0 && j < F_HW) wt = keys_w(fabsf(sf - (float)j));
        w[t] = wt;
        sum += wt;
    }
    float inv = 1.0f / sum;
#pragma unroll
    for (int t = 0; t < 4; ++t) w[t] *= inv;
    return jf - 1;
}

__global__ __launch_bounds__(256, 4) void sdt_kernel(const float* __restrict__ U,
                                                     const float* __restrict__ flow,
                                                     float* __restrict__ out) {
    __shared__ float  wx4[TILE][4];
    __shared__ int    jx0s[TILE];
    __shared__ float  wy4[TILE][4];
    __shared__ int    djy[TILE];          // y-tap base relative to jyB (0..2)
    __shared__ float2 Hs[6][TILE + 1];    // horizontal pass result (+1 pad)
    __shared__ float2 coords[TILE * TILE];

    const int tid = threadIdx.x;
    // XCD-chunked swizzle: round-robin wg->XCD means bid&7 == XCD id.
    const int b  = blockIdx.x & 7;
    const int t  = blockIdx.x >> 3;          // 0..1023 tile within image
    const int tx = t & 31;
    const int ty = t >> 5;
    const int jxB = 2 * tx - 2;              // closed-form x-tap base for tile
    const int jyB = 2 * ty - 2;              // closed-form y-tap base for tile

    const float* fb = flow + (size_t)b * (F_HW * F_HW * 2);

    // ---- step A: per-column x-taps (thr 0-15), per-row y-taps (thr 16-31) ----
    if (tid < 16) {
        float w[4];
        const int base = cubic_taps(tx * TILE + tid, w);
        wx4[tid][0] = w[0]; wx4[tid][1] = w[1]; wx4[tid][2] = w[2]; wx4[tid][3] = w[3];
        jx0s[tid] = base;
    } else if (tid < 32) {
        const int py = tid - 16;
        float w[4];
        const int base = cubic_taps(ty * TILE + py, w);
        wy4[py][0] = w[0]; wy4[py][1] = w[1]; wy4[py][2] = w[2]; wy4[py][3] = w[3];
        djy[py] = base - jyB;               // 0..2
    }
    __syncthreads();

    // ---- step B: horizontal pass, 6 flow rows x 16 columns ----
    if (tid < 96) {
        const int jrow = tid >> 4;           // 0..5
        const int col  = tid & 15;
        const int row  = min(max(jyB + jrow, 0), F_HW - 1);
        const float2* frow = (const float2*)fb + row * F_HW;
        const int base = jx0s[col];
        float hx = 0.0f, hy = 0.0f;
#pragma unroll
        for (int r = 0; r < 4; ++r) {
            const int jx = min(max(base + r, 0), F_HW - 1);
            const float w = wx4[col][r];
            const float2 f2 = frow[jx];
            hx = fmaf(w, f2.x, hx);
            hy = fmaf(w, f2.y, hy);
        }
        Hs[jrow][col] = make_float2(hx, hy);
    }
    __syncthreads();

    // ---- step C: vertical pass + grid transform, one pixel per thread ----
    {
        const int px = tid & 15;
        const int py = tid >> 4;
        const int dj = djy[py];
        float vx = 0.0f, vy = 0.0f;
#pragma unroll
        for (int s = 0; s < 4; ++s) {
            const float w = wy4[py][s];
            const float2 h = Hs[dj + s][px];
            vx = fmaf(w, h.x, vx);
            vy = fmaf(w, h.y, vy);
        }
        const int ox = tx * TILE + px;
        const int oy = ty * TILE + py;
        const float xg = -1.0f + (2.0f / 511.0f) * (float)ox;
        const float yg = -1.0f + (2.0f / 511.0f) * (float)oy;
        // reference: x = (xs + 1) * W/2  (NOT (W-1)/2)
        coords[tid] = make_float2((vx + xg + 1.0f) * (IN_HW / 2.0f),
                                  (vy + yg + 1.0f) * (IN_HW / 2.0f));
    }
    __syncthreads();

    // ---- phase 2: 4 passes, 4 threads per pixel ----
    const int chg  = tid & 3;          // channel group (float4)
    const int slot = tid >> 2;         // 0..63
    const float* Ub = U + (size_t)b * (IN_HW * IN_HW * N_C);
#pragma unroll
    for (int it = 0; it < 4; ++it) {
        const int q  = it * 64 + slot;         // pixel within tile
        const float2 c = coords[q];
        const float x = c.x, y = c.y;

        const float fx0 = floorf(x);
        const float fy0 = floorf(y);
        const int x0 = min(max((int)fx0, 0), IN_HW - 1);
        const int x1 = min(max((int)fx0 + 1, 0), IN_HW - 1);
        const int y0 = min(max((int)fy0, 0), IN_HW - 1);
        const int y1 = min(max((int)fy0 + 1, 0), IN_HW - 1);
        // weights from CLIPPED corner coords (replicates reference exactly)
        const float x0f = (float)x0, x1f = (float)x1, y0f = (float)y0, y1f = (float)y1;
        const float wa = (x1f - x) * (y1f - y);
        const float wb = (x1f - x) * (y - y0f);
        const float wc = (x - x0f) * (y1f - y);
        const float wd = (x - x0f) * (y - y0f);

        const fvec4 a  = *((const fvec4*)(Ub + ((size_t)y0 * IN_HW + x0) * N_C) + chg);
        const fvec4 bb = *((const fvec4*)(Ub + ((size_t)y1 * IN_HW + x0) * N_C) + chg);
        const fvec4 cc = *((const fvec4*)(Ub + ((size_t)y0 * IN_HW + x1) * N_C) + chg);
        const fvec4 dd = *((const fvec4*)(Ub + ((size_t)y1 * IN_HW + x1) * N_C) + chg);
        const fvec4 r = wa * a + wb * bb + wc * cc + wd * dd;

        const int ox = tx * TILE + (q & 15);
        const int oy = ty * TILE + (q >> 4);
        fvec4* O = (fvec4*)(out + (((size_t)b * OUTHW + oy) * OUTHW + ox) * N_C) + chg;
        __builtin_nontemporal_store(r, O);   // write-once stream: keep U in L3
    }
}

extern "C" void kernel_launch(void* const* d_in, const int* in_sizes, int n_in,
                              void* d_out, int out_size, void* d_ws, size_t ws_size,
                              hipStream_t stream) {
    const float* U    = (const float*)d_in[0];
    const float* flow = (const float*)d_in[1];
    float* out        = (float*)d_out;
    const int n_blocks = N_B * (OUTHW / TILE) * (OUTHW / TILE);  // 8192
    sdt_kernel<<<dim3(n_blocks), dim3(256), 0, stream>>>(U, flow, out);
}